// Round 12
// baseline (564.252 us; speedup 1.0000x reference)
//
#include <hip/hip_runtime.h>
#include <hip/hip_bf16.h>

// Int8Linear: out[B,T,OUT] = x[B,T,IN] @ (w_int8*scale)^T + bias
// M = B*T = 8192, N = OUT = 11008, K = IN = 4096
// Full-int8: x per-token absmax-quantized, W exact i8, mfma_i32_16x16x64_i8.
// R12: 2-blocks/CU for real. R11 failed because acc[8][4]=128 AGPRs pushed
// true per-wave regs to ~240 (CSV VGPR_Count=112 excludes AGPR) -> 1 block.
// New shape: BM=128, BN=256, per-wave out 64x64 -> acc[4][4]=64 regs,
// frags 32, total ~120 <= 128 -> 4 waves/SIMD -> 2 blocks/CU. LDS ring-3 =
// 72KB (144KB for 2 blocks <= 160). Cross-block wave overlap (m114) hides
// the additive {ds_read}+{MFMA}+{barrier} stall all 1-block schedules hit.
#define MDIM 8192
#define NDIM 11008
#define KDIM 4096

#define BM 128
#define BN 256
#define BK 64
#define NT (KDIM / BK)   // 64 K-tiles

typedef __attribute__((ext_vector_type(4))) int int4v;

// ---------------- x quantization: per-token absmax -> i8 ----------------

__global__ __launch_bounds__(256) void quant_x_kernel(const float* __restrict__ x,
                                                      int* __restrict__ q,
                                                      float* __restrict__ xs) {
  int row = blockIdx.x;
  int tid = threadIdx.x;
  const float4* xr = (const float4*)(x + (size_t)row * KDIM);
  float4 v[4];
  float amax = 0.f;
#pragma unroll
  for (int i = 0; i < 4; ++i) {
    v[i] = xr[tid + i * 256];
    amax = fmaxf(amax, fmaxf(fmaxf(fabsf(v[i].x), fabsf(v[i].y)),
                             fmaxf(fabsf(v[i].z), fabsf(v[i].w))));
  }
#pragma unroll
  for (int off = 32; off; off >>= 1)
    amax = fmaxf(amax, __shfl_xor(amax, off));
  __shared__ float smax[4];
  if ((tid & 63) == 0) smax[tid >> 6] = amax;
  __syncthreads();
  amax = fmaxf(fmaxf(smax[0], smax[1]), fmaxf(smax[2], smax[3]));
  amax = fmaxf(amax, 1e-20f);
  float inv = 127.f / amax;
  if (tid == 0) xs[row] = amax * (1.f / 127.f);
  int* qr = q + (size_t)row * (KDIM / 4);
#pragma unroll
  for (int i = 0; i < 4; ++i) {
    int a = (int)rintf(v[i].x * inv) & 255;
    int b = (int)rintf(v[i].y * inv) & 255;
    int c = (int)rintf(v[i].z * inv) & 255;
    int d = (int)rintf(v[i].w * inv);
    qr[tid + i * 256] = a | (b << 8) | (c << 16) | (d << 24);
  }
}

// ---------------- W pack: int32 -> i8 (exact) ----------------

__global__ void cvt_w_kernel(const int* __restrict__ w, int* __restrict__ q, int n) {
  int stride = gridDim.x * blockDim.x;
  for (int i = blockIdx.x * blockDim.x + threadIdx.x; i < n; i += stride) {
    int4v v = *(const int4v*)(w + (size_t)i * 4);
    q[i] = (v.x & 255) | ((v.y & 255) << 8) | ((v.z & 255) << 16) | (v.w << 24);
  }
}

// ---------------- 128x256 int8 MFMA GEMM (ring-3, 2 blocks/CU) ------
// LDS: A [3][128][64] = 24KB, B [3][256][64] = 48KB; total 72KB.
// Tile T = {8 ds_read_b128 (slot T%3), stage A+B of T+2 (slot (T+2)%3),
//           16 MFMA, vmcnt(3), 1 barrier}.  Counted vmcnt: T+1 landed,
//           T+2's 3 loads stay in flight.

#define SBARR() __builtin_amdgcn_sched_barrier(0)
#define BARR()  __builtin_amdgcn_s_barrier()
#define VMW_(n) asm volatile("s_waitcnt vmcnt(" #n ")" ::: "memory")
#define VMW(n)  VMW_(n)

#define GLL(SRC, DST) \
  __builtin_amdgcn_global_load_lds( \
      (const __attribute__((address_space(1))) void*)(SRC), \
      (__attribute__((address_space(3))) void*)(DST), 16, 0, 0)

// A K-tile (8KB): 1 load/thread. B K-tile (16KB): 2 loads/thread.
#define STAGE_A(BUFI, T) \
  GLL(gAs + (T) * 64, ldsA + (BUFI) * 8192 + w * 1024)
#define STAGE_B(BUFI, T) do { \
    GLL(gBs + (T) * 64,         ldsB + (BUFI) * 16384 + w * 1024); \
    GLL(gBs + (T) * 64 + rstep, ldsB + (BUFI) * 16384 + 8192 + w * 1024); \
  } while (0)

// swizzled fragment read (16B = 16 i8 along K for one row)
#define RDA(BUFI, ROW) (*(const int4v*)(ldsA + (BUFI) * 8192  + (ROW) * 64 + kbs))
#define RDB(BUFI, ROW) (*(const int4v*)(ldsB + (BUFI) * 16384 + (ROW) * 64 + kbs))

// One K-tile. SLT = T%3 (compile-time), SS = slot for T+2, SD = stage T+2,
// VN = vmcnt arg, TAIL = last tile.
#define KT(T, SLT, SS, SD, VN, TAIL) do { \
    _Pragma("unroll") for (int ni = 0; ni < 4; ++ni) bf[ni] = RDB(SLT, brow0 + ni * 16); \
    _Pragma("unroll") for (int mi = 0; mi < 4; ++mi) af[mi] = RDA(SLT, arow0 + mi * 16); \
    if (SD) { STAGE_A(SS, (T) + 2); STAGE_B(SS, (T) + 2); } \
    SBARR(); \
    __builtin_amdgcn_s_setprio(1); \
    _Pragma("unroll") for (int mi = 0; mi < 4; ++mi) \
    _Pragma("unroll") for (int ni = 0; ni < 4; ++ni) \
      acc[mi][ni] = __builtin_amdgcn_mfma_i32_16x16x64_i8( \
          af[mi], bf[ni], acc[mi][ni], 0, 0, 0); \
    __builtin_amdgcn_s_setprio(0); \
    SBARR(); \
    if (!(TAIL)) { VMW(VN); BARR(); SBARR(); } \
  } while (0)

__global__ __launch_bounds__(512, 2) void gemm_i8_kernel(
    const char* __restrict__ A,
    const char* __restrict__ Bt,
    const float* __restrict__ xs,
    const float* __restrict__ scale,
    const float* __restrict__ bias,
    float* __restrict__ C)
{
  __shared__ __attribute__((aligned(16))) char As[3][128][64];  // 24 KB
  __shared__ __attribute__((aligned(16))) char Bs[3][256][64];  // 48 KB

  // grid = (8192/128) * (11008/256) = 64*43 = 2752 = 8*344
  int bid = blockIdx.x;
  int cpx = gridDim.x >> 3;                 // 344
  int swz = (bid & 7) * cpx + (bid >> 3);   // bijective XCD swizzle
  // 16x4 supertile (64 blocks share 16 A + 4 B panels = 12 MB/XCD).
  // band = 16 brows x 43 bcols = 688 blocks; ragged last col group (16x3).
  int band = swz / 688;
  int rem  = swz - band * 688;
  int scol, q;
  if (rem < 640) { scol = rem >> 6;  q = rem & 63; }
  else           { scol = 10;        q = rem - 640; }
  int brow, bcol;
  if (rem < 640) { brow = (band * 16 + (q & 15)) * BM; bcol = (scol * 4 + (q >> 4)) * BN; }
  else           { brow = (band * 16 + (q & 15)) * BM; bcol = (40 + (q >> 4)) * BN; }

  int tid  = threadIdx.x;
  int lane = tid & 63;
  int w    = tid >> 6;
  int wr   = w >> 2;         // M-wave (2)
  int wc   = w & 3;          // N-wave (4)

  int ra = lane & 15;                         // fragment row within 16
  int kb = (lane >> 4) * 16;                  // byte offset along K (64B row)
  int kbs = kb ^ (((ra >> 1) & 3) << 4);      // proven 0-conflict swizzle

  int arow0 = wr * 64 + ra;                   // wave's A base row + frag row
  int brow0 = wc * 64 + ra;                   // wave's B base row + frag row

  // staging: thread granule g = tid -> row g>>2, dst granule g&3;
  // inverse-swizzled source k-granule (same proven formula)
  int srw  = tid >> 2;
  int csrc = (tid & 3) ^ ((tid >> 3) & 3);
  const char* gAs = A  + (size_t)(brow + srw) * KDIM + csrc * 16;
  const char* gBs = Bt + (size_t)(bcol + srw) * KDIM + csrc * 16;
  const size_t rstep = (size_t)128 * KDIM;

  char* ldsA = &As[0][0][0];
  char* ldsB = &Bs[0][0][0];

  int4v acc[4][4] = {};
  int4v af[4], bf[4];

  // prologue: tiles 0,1 into slots 0,1 (6 loads); vmcnt(3) -> tile 0 landed
  STAGE_A(0, 0);  STAGE_B(0, 0);
  STAGE_A(1, 1);  STAGE_B(1, 1);
  VMW(3); BARR(); SBARR();

  // steady: tiles 0..59 (stage T+2 into slot (T+2)%3, vmcnt(3))
  for (int t = 0; t < 60; t += 3) {
    KT(t,     0, 2, 1, 3, 0);
    KT(t + 1, 1, 0, 1, 3, 0);
    KT(t + 2, 2, 1, 1, 3, 0);
  }
  KT(60, 0, 2, 1, 3, 0);   // stages 62
  KT(61, 1, 0, 1, 3, 0);   // stages 63
  KT(62, 2, 0, 0, 0, 0);   // no stage; drain 63
  KT(63, 0, 0, 0, 0, 1);   // last tile

  // epilogue: C/D layout col = lane&15, row = (lane>>4)*4 + reg
  int col0 = bcol + wc * 64 + ra;
  int row0 = brow + wr * 64 + (lane >> 4) * 4;
#pragma unroll
  for (int n = 0; n < 4; ++n) {
    int ng = col0 + n * 16;
    float sc = scale[ng];
    float bi = bias[ng];
#pragma unroll
    for (int m = 0; m < 4; ++m) {
      int rg = row0 + m * 16;
#pragma unroll
      for (int j = 0; j < 4; ++j)
        __builtin_nontemporal_store(
            (float)acc[m][n][j] * (xs[rg + j] * sc) + bi,
            &C[(size_t)(rg + j) * NDIM + ng]);
    }
  }
}

// ---------------- fallback (only if d_ws is too small) ----------------

__global__ void naive_kernel(const float* __restrict__ x, const int* __restrict__ w,
                             const float* __restrict__ scale, const float* __restrict__ bias,
                             float* __restrict__ out)
{
  int n = blockIdx.x * blockDim.x + threadIdx.x;
  int m = blockIdx.y;
  if (n >= NDIM) return;
  const float* xr = x + (size_t)m * KDIM;
  const int* wrow = w + (size_t)n * KDIM;
  float s = 0.f;
  for (int k = 0; k < KDIM; ++k) s += xr[k] * (float)wrow[k];
  out[(size_t)m * NDIM + n] = s * scale[n] + bias[n];
}

// ---------------- launcher ----------------

extern "C" void kernel_launch(void* const* d_in, const int* in_sizes, int n_in,
                              void* d_out, int out_size, void* d_ws, size_t ws_size,
                              hipStream_t stream) {
  const float* x      = (const float*)d_in[0];
  const int*   w8     = (const int*)d_in[1];
  const float* wscale = (const float*)d_in[2];
  const float* bias   = (const float*)d_in[3];
  float* out = (float*)d_out;

  size_t aq = (size_t)MDIM * KDIM;   // 33.5 MB i8
  size_t bq = (size_t)NDIM * KDIM;   // 45.1 MB i8
  size_t xb = (size_t)MDIM * 4;      // 32 KB scales

  if (ws_size >= aq + bq + xb) {
    char* Aq = (char*)d_ws;
    char* Bq = (char*)d_ws + aq;
    float* xsp = (float*)((char*)d_ws + aq + bq);
    quant_x_kernel<<<MDIM, 256, 0, stream>>>(x, (int*)Aq, xsp);
    cvt_w_kernel<<<2048, 256, 0, stream>>>(w8, (int*)Bq, NDIM * KDIM / 4);
    gemm_i8_kernel<<<(MDIM / BM) * (NDIM / BN), 512, 0, stream>>>(
        Aq, Bq, xsp, wscale, bias, out);
  } else {
    naive_kernel<<<dim3((NDIM + 255) / 256, MDIM), 256, 0, stream>>>(x, w8, wscale, bias, out);
  }
}

// Round 13
// 506.797 us; speedup vs baseline: 1.1134x; 1.1134x over previous
//
#include <hip/hip_runtime.h>
#include <hip/hip_bf16.h>

// Int8Linear: out[B,T,OUT] = x[B,T,IN] @ (w_int8*scale)^T + bias
// M = B*T = 8192, N = OUT = 11008, K = IN = 4096
// Full-int8: x per-token absmax-quantized, W exact i8, mfma_i32_16x16x64_i8.
// R13: m201-faithful 8-barrier-pair phase cadence on the proven R6/R9
// substrate (256x256 tile, ring-4 LDS, 0-conflict swizzle, supertile map).
// Per K-tile: 4 phases {reads + 1 stage-GLL; barrier; lgkm0; 8 MFMA;
// barrier}, vmcnt(4) once per tile. This is the one m201 element never
// tried here (R6/R7/R8 were 1-2 coarse phases); catalog A/B (m196/m248)
// isolates this fine interleave as the 8-phase lever.
#define MDIM 8192
#define NDIM 11008
#define KDIM 4096

#define BM 256
#define BN 256
#define BK 64
#define NT (KDIM / BK)   // 64 K-tiles

typedef __attribute__((ext_vector_type(4))) int int4v;

// ---------------- x quantization: per-token absmax -> i8 ----------------

__global__ __launch_bounds__(256) void quant_x_kernel(const float* __restrict__ x,
                                                      int* __restrict__ q,
                                                      float* __restrict__ xs) {
  int row = blockIdx.x;
  int tid = threadIdx.x;
  const float4* xr = (const float4*)(x + (size_t)row * KDIM);
  float4 v[4];
  float amax = 0.f;
#pragma unroll
  for (int i = 0; i < 4; ++i) {
    v[i] = xr[tid + i * 256];
    amax = fmaxf(amax, fmaxf(fmaxf(fabsf(v[i].x), fabsf(v[i].y)),
                             fmaxf(fabsf(v[i].z), fabsf(v[i].w))));
  }
#pragma unroll
  for (int off = 32; off; off >>= 1)
    amax = fmaxf(amax, __shfl_xor(amax, off));
  __shared__ float smax[4];
  if ((tid & 63) == 0) smax[tid >> 6] = amax;
  __syncthreads();
  amax = fmaxf(fmaxf(smax[0], smax[1]), fmaxf(smax[2], smax[3]));
  amax = fmaxf(amax, 1e-20f);
  float inv = 127.f / amax;
  if (tid == 0) xs[row] = amax * (1.f / 127.f);
  int* qr = q + (size_t)row * (KDIM / 4);
#pragma unroll
  for (int i = 0; i < 4; ++i) {
    int a = (int)rintf(v[i].x * inv) & 255;
    int b = (int)rintf(v[i].y * inv) & 255;
    int c = (int)rintf(v[i].z * inv) & 255;
    int d = (int)rintf(v[i].w * inv);
    qr[tid + i * 256] = a | (b << 8) | (c << 16) | (d << 24);
  }
}

// ---------------- W pack: int32 -> i8 (exact) ----------------

__global__ void cvt_w_kernel(const int* __restrict__ w, int* __restrict__ q, int n) {
  int stride = gridDim.x * blockDim.x;
  for (int i = blockIdx.x * blockDim.x + threadIdx.x; i < n; i += stride) {
    int4v v = *(const int4v*)(w + (size_t)i * 4);
    q[i] = (v.x & 255) | ((v.y & 255) << 8) | ((v.z & 255) << 16) | (v.w << 24);
  }
}

// ---------------- 256x256 int8 MFMA GEMM (ring-4, 4-phase cadence) ------
// LDS: per operand [4-ring][256 rows][64 B] = 64 KB; total 128 KB.
// Phase p of tile T (Gray order over C-quadrants):
//   P0: read afL(m0-3)+bfL(n0-1) [6]; stage A-lo(T+2); B; lgkm0; MFMA q(0,0)
//   P1: read bfH(n2-3)           [2]; stage A-hi(T+2); B; lgkm0; MFMA q(0,1)
//   P2: read afH(m4-7)           [4]; stage B-lo(T+2); B; lgkm0; MFMA q(1,1)
//   P3: (no reads)                  ; stage B-hi(T+2); B; lgkm0; MFMA q(1,0)
//       vmcnt(4); barrier.
// Invariant entering T: slot T landed; T+1's 4 loads outstanding max.

#define SBARR() __builtin_amdgcn_sched_barrier(0)
#define BARR()  __builtin_amdgcn_s_barrier()
#define LGK0()  asm volatile("s_waitcnt lgkmcnt(0)" ::: "memory")
#define VMW_(n) asm volatile("s_waitcnt vmcnt(" #n ")" ::: "memory")
#define VMW(n)  VMW_(n)

#define GLL(SRC, DST) \
  __builtin_amdgcn_global_load_lds( \
      (const __attribute__((address_space(1))) void*)(SRC), \
      (__attribute__((address_space(3))) void*)(DST), 16, 0, 0)

// one 8KB half-unit per GLL call site (512 thr x 16B); addresses identical
// to the proven R6 STAGE split into its two halves
#define STAGE_A_LO(BUFI, T) GLL(gAs + (T) * 64,         ldsA + (BUFI) * 16384 + w * 1024)
#define STAGE_A_HI(BUFI, T) GLL(gAs + (T) * 64 + rstep, ldsA + (BUFI) * 16384 + 8192 + w * 1024)
#define STAGE_B_LO(BUFI, T) GLL(gBs + (T) * 64,         ldsB + (BUFI) * 16384 + w * 1024)
#define STAGE_B_HI(BUFI, T) GLL(gBs + (T) * 64 + rstep, ldsB + (BUFI) * 16384 + 8192 + w * 1024)

// swizzled fragment read (16B = 16 i8 along K for one row)
#define RDA(BUFI, ROW) (*(const int4v*)(ldsA + (BUFI) * 16384 + (ROW) * 64 + kbs))
#define RDB(BUFI, ROW) (*(const int4v*)(ldsB + (BUFI) * 16384 + (ROW) * 64 + kbs))

// 8 MFMA = one C-quadrant (4 m-blocks x 2 n-blocks)
#define MFMA8(AF, BF, MH, NH) do { \
    _Pragma("unroll") for (int mi = 0; mi < 4; ++mi) \
    _Pragma("unroll") for (int ni = 0; ni < 2; ++ni) \
      acc[(MH) * 4 + mi][(NH) * 2 + ni] = __builtin_amdgcn_mfma_i32_16x16x64_i8( \
          AF[mi], BF[ni], acc[(MH) * 4 + mi][(NH) * 2 + ni], 0, 0, 0); \
  } while (0)

// One K-tile = 4 phases. SLT = T&3 (literal). SD: stage T+2. DW: do end wait
// VMW(VN). LAST: final tile (no trailing barrier).
#define KTILE(T, SLT, SD, DW, VN, LAST) do { \
    const int _ss = ((SLT) + 2) & 3; \
    /* P0 */ \
    _Pragma("unroll") for (int mi = 0; mi < 4; ++mi) afL[mi] = RDA(SLT, arow0 + mi * 16); \
    bfL[0] = RDB(SLT, brow0);      bfL[1] = RDB(SLT, brow0 + 16); \
    if (SD) STAGE_A_LO(_ss, (T) + 2); \
    SBARR(); BARR(); LGK0(); SBARR(); \
    __builtin_amdgcn_s_setprio(1); MFMA8(afL, bfL, 0, 0); __builtin_amdgcn_s_setprio(0); \
    SBARR(); BARR(); SBARR(); \
    /* P1 */ \
    bfH[0] = RDB(SLT, brow0 + 32); bfH[1] = RDB(SLT, brow0 + 48); \
    if (SD) STAGE_A_HI(_ss, (T) + 2); \
    SBARR(); BARR(); LGK0(); SBARR(); \
    __builtin_amdgcn_s_setprio(1); MFMA8(afL, bfH, 0, 1); __builtin_amdgcn_s_setprio(0); \
    SBARR(); BARR(); SBARR(); \
    /* P2 */ \
    _Pragma("unroll") for (int mi = 0; mi < 4; ++mi) afH[mi] = RDA(SLT, arow0 + 64 + mi * 16); \
    if (SD) STAGE_B_LO(_ss, (T) + 2); \
    SBARR(); BARR(); LGK0(); SBARR(); \
    __builtin_amdgcn_s_setprio(1); MFMA8(afH, bfH, 1, 1); __builtin_amdgcn_s_setprio(0); \
    SBARR(); BARR(); SBARR(); \
    /* P3 */ \
    if (SD) STAGE_B_HI(_ss, (T) + 2); \
    SBARR(); BARR(); LGK0(); SBARR(); \
    __builtin_amdgcn_s_setprio(1); MFMA8(afH, bfL, 1, 0); __builtin_amdgcn_s_setprio(0); \
    SBARR(); \
    if (DW) { VMW(VN); } \
    if (!(LAST)) { BARR(); SBARR(); } \
  } while (0)

__global__ __launch_bounds__(512, 2) void gemm_i8_kernel(
    const char* __restrict__ A,
    const char* __restrict__ Bt,
    const float* __restrict__ xs,
    const float* __restrict__ scale,
    const float* __restrict__ bias,
    float* __restrict__ C)
{
  __shared__ __attribute__((aligned(16))) char As[4][256][64];  // 64 KB
  __shared__ __attribute__((aligned(16))) char Bs[4][256][64];  // 64 KB

  // grid = 32*43 = 1376 = 8*172
  int bid = blockIdx.x;
  int cpx = gridDim.x >> 3;                 // 172
  int swz = (bid & 7) * cpx + (bid >> 3);   // bijective XCD swizzle
  // 8x4 supertile order (bijective; ragged last col 8x3) — R9's proven map
  int srow = swz / 344;
  int rem  = swz - srow * 344;
  int scol, q;
  if (rem < 320) { scol = rem >> 5; q = rem & 31; }
  else           { scol = 10;       q = rem - 320; }
  int brow = (srow * 8 + (q & 7)) * BM;
  int bcol = (scol * 4 + (q >> 3)) * BN;

  int tid  = threadIdx.x;
  int lane = tid & 63;
  int w    = tid >> 6;
  int wr   = (w >> 2) & 1;   // M-wave (2)
  int wc   = w & 3;          // N-wave (4)

  int ra = lane & 15;                         // fragment row within 16
  int kb = (lane >> 4) * 16;                  // byte offset along K (64B row)
  int kbs = kb ^ (((ra >> 1) & 3) << 4);      // proven 0-conflict swizzle

  int arow0 = wr * 128 + ra;                  // wave's A base row + frag row
  int brow0 = wc * 64 + ra;                   // wave's B base row + frag row

  // staging: thread granule g = w*64+lane -> (row srw, dst granule lane&3);
  // inverse-swizzled source k-granule (lane-constant)
  int srw = w * 16 + (lane >> 2);
  int csrc = (lane & 3) ^ ((lane >> 3) & 3);
  const char* gAs = A  + (size_t)(brow + srw) * KDIM + csrc * 16;
  const char* gBs = Bt + (size_t)(bcol + srw) * KDIM + csrc * 16;
  const size_t rstep = (size_t)128 * KDIM;

  char* ldsA = &As[0][0][0];
  char* ldsB = &Bs[0][0][0];

  int4v acc[8][4] = {};
  int4v afL[4], afH[4], bfL[2], bfH[2];

  // prologue: tiles 0,1 into slots 0,1 (8 GLL); vmcnt(4) -> tile 0 landed,
  // tile 1's 4 outstanding (= steady invariant entering tile 0)
  STAGE_A_LO(0, 0); STAGE_A_HI(0, 0); STAGE_B_LO(0, 0); STAGE_B_HI(0, 0);
  STAGE_A_LO(1, 1); STAGE_A_HI(1, 1); STAGE_B_LO(1, 1); STAGE_B_HI(1, 1);
  VMW(4); BARR(); SBARR();

  // steady: tiles 0..59 (stage T+2 one half-unit per phase, vmcnt(4)/tile)
  for (int t = 0; t < 60; t += 4) {
    KTILE(t,     0, 1, 1, 4, 0);
    KTILE(t + 1, 1, 1, 1, 4, 0);
    KTILE(t + 2, 2, 1, 1, 4, 0);
    KTILE(t + 3, 3, 1, 1, 4, 0);
  }
  KTILE(60, 0, 1, 1, 4, 0);   // stages 62
  KTILE(61, 1, 1, 1, 4, 0);   // stages 63
  KTILE(62, 2, 0, 1, 0, 0);   // no stage; drain -> 63 landed
  KTILE(63, 3, 0, 0, 0, 1);   // last tile

  // epilogue: C/D layout col = lane&15, row = (lane>>4)*4 + reg (dtype-indep)
  // non-temporal stores: write stream must not churn L2/L3
  int col0 = bcol + wc * 64 + ra;
  int row0 = brow + wr * 128 + (lane >> 4) * 4;
  float xr_[8][4];
#pragma unroll
  for (int m = 0; m < 8; ++m)
#pragma unroll
    for (int j = 0; j < 4; ++j)
      xr_[m][j] = xs[row0 + m * 16 + j];
#pragma unroll
  for (int n = 0; n < 4; ++n) {
    int ng = col0 + n * 16;
    float sc = scale[ng];
    float bi = bias[ng];
#pragma unroll
    for (int m = 0; m < 8; ++m) {
      int rg = row0 + m * 16;
#pragma unroll
      for (int j = 0; j < 4; ++j)
        __builtin_nontemporal_store((float)acc[m][n][j] * (xr_[m][j] * sc) + bi,
                                    &C[(size_t)(rg + j) * NDIM + ng]);
    }
  }
}

// ---------------- fallback (only if d_ws is too small) ----------------

__global__ void naive_kernel(const float* __restrict__ x, const int* __restrict__ w,
                             const float* __restrict__ scale, const float* __restrict__ bias,
                             float* __restrict__ out)
{
  int n = blockIdx.x * blockDim.x + threadIdx.x;
  int m = blockIdx.y;
  if (n >= NDIM) return;
  const float* xr = x + (size_t)m * KDIM;
  const int* wrow = w + (size_t)n * KDIM;
  float s = 0.f;
  for (int k = 0; k < KDIM; ++k) s += xr[k] * (float)wrow[k];
  out[(size_t)m * NDIM + n] = s * scale[n] + bias[n];
}

// ---------------- launcher ----------------

extern "C" void kernel_launch(void* const* d_in, const int* in_sizes, int n_in,
                              void* d_out, int out_size, void* d_ws, size_t ws_size,
                              hipStream_t stream) {
  const float* x      = (const float*)d_in[0];
  const int*   w8     = (const int*)d_in[1];
  const float* wscale = (const float*)d_in[2];
  const float* bias   = (const float*)d_in[3];
  float* out = (float*)d_out;

  size_t aq = (size_t)MDIM * KDIM;   // 33.5 MB i8
  size_t bq = (size_t)NDIM * KDIM;   // 45.1 MB i8
  size_t xb = (size_t)MDIM * 4;      // 32 KB scales

  if (ws_size >= aq + bq + xb) {
    char* Aq = (char*)d_ws;
    char* Bq = (char*)d_ws + aq;
    float* xsp = (float*)((char*)d_ws + aq + bq);
    quant_x_kernel<<<MDIM, 256, 0, stream>>>(x, (int*)Aq, xsp);
    cvt_w_kernel<<<2048, 256, 0, stream>>>(w8, (int*)Bq, NDIM * KDIM / 4);
    gemm_i8_kernel<<<(MDIM / BM) * (NDIM / BN), 512, 0, stream>>>(
        Aq, Bq, xsp, wscale, bias, out);
  } else {
    naive_kernel<<<dim3((NDIM + 255) / 256, MDIM), 256, 0, stream>>>(x, w8, wscale, bias, out);
  }
}